// Round 1
// baseline (495.334 us; speedup 1.0000x reference)
//
#include <hip/hip_runtime.h>
#include <hip/hip_bf16.h>

#define SEQ   4096
#define BATCH 32
#define HID   512
#define MTOT  (SEQ * BATCH)   // 131072

typedef float  f32x4  __attribute__((ext_vector_type(4)));
typedef __bf16 bf16x8 __attribute__((ext_vector_type(8)));

__device__ __forceinline__ unsigned short f2bf(float f) {
    unsigned int u = __builtin_bit_cast(unsigned int, f);
    u = (u + 0x7fffu + ((u >> 16) & 1u)) >> 16;   // RNE
    return (unsigned short)u;
}

// HW packed convert: dst = (bf16(hi)<<16) | bf16(lo), RNE — 1 inst per 2 floats
__device__ __forceinline__ unsigned int cvt_pk(float lo, float hi) {
    unsigned int r;
    asm("v_cvt_pk_bf16_f32 %0, %1, %2" : "=v"(r) : "v"(lo), "v"(hi));
    return r;
}

__device__ __forceinline__ float tanh_fast(float x) {
    float ax = fabsf(x);
    float e  = __expf(-2.0f * ax);           // in (0,1]
    float t  = (1.0f - e) * __builtin_amdgcn_rcpf(1.0f + e);
    return copysignf(t, x);
}

// ---- kernel 1: W fp32 -> bf16 ------------------------------------------
__global__ __launch_bounds__(256) void cvt_w_kernel(const float* __restrict__ W,
                                                    unsigned short* __restrict__ Wb) {
    int i = (blockIdx.x * 256 + threadIdx.x) * 4;
    float4 f = *(const float4*)(W + i);
    ushort4 u;
    u.x = f2bf(f.x); u.y = f2bf(f.y); u.z = f2bf(f.z); u.w = f2bf(f.w);
    *(ushort4*)(Wb + i) = u;
}

// ---- kernel 2: fused GEMM + tanh + ctx-dot -> sims ---------------------
// y[m,o] = sum_k x[m,k]*W[o,k];  sims[b][s] += sum_o ctx[o]*tanh(y+bias[o])
#define BM 128
#define BN 128
#define BK 64
#define LDSP 72   // padded LDS stride for A (bf16 elems); 144 B = 9*16 B

__global__ __launch_bounds__(256) void gemm_sim_kernel(
    const float* __restrict__ x, const unsigned short* __restrict__ Wb,
    const float* __restrict__ bias, const float* __restrict__ ctx,
    float* __restrict__ sims)
{
    __shared__ unsigned short As[BM][LDSP];   // reg-staged (fp32->bf16), pad-72
    __shared__ unsigned short Bs[BN][BK];     // linear 128B rows, XOR-swizzled content

    // XCD-chunked swizzle: 4096 blocks, 8 XCDs, 512 work-ids/XCD; within an
    // XCD nt is fastest -> the 4 n-tiles of one mt co-resident on ONE XCD,
    // so the x A-tile is L2-served after its first HBM fetch.
    const int bid = blockIdx.x;
    const int wid = (bid & 7) * 512 + (bid >> 3);
    const int nt  = wid & 3;          // 0..3
    const int mt  = wid >> 2;         // 0..1023

    const int tid  = threadIdx.x;
    const int lane = tid & 63;
    const int wave = tid >> 6;
    const int wm = wave >> 1, wn = wave & 1;
    const int l15 = lane & 15, q = lane >> 4;

    const int rbase = tid >> 3;         // 0..31
    const int kc    = (tid & 7) * 8;    // 0..56

    // B global_load_lds addressing: wave covers rows wave*32..wave*32+31 in
    // 4 instrs of 1KB (8 rows each). LDS dest is LINEAR; the global source
    // is pre-swizzled so that a read at slot s of row r returns k-chunk
    // s ^ (r&7)  (involution -> both-sides-consistent).
    const int brow   = wave * 32 + (lane >> 3);   // + j*8
    const int bslot  = lane & 7;
    const int bchunk = bslot ^ (brow & 7);        // j*8 doesn't change row&7
    const unsigned short* bptr = Wb + (size_t)(nt * BN + brow) * HID + bchunk * 8;
    const float* aptr = x + (size_t)(mt * BM + rbase) * HID + kc;

    f32x4 acc[4][4] = {};

    for (int kt = 0; kt < HID / BK; ++kt) {
        const int k0 = kt * BK;
        // B: 4x global_load_lds dwordx4 (no VGPR round-trip)
        #pragma unroll
        for (int j = 0; j < 4; ++j) {
            __builtin_amdgcn_global_load_lds(
                (const __attribute__((address_space(1))) void*)(bptr + (size_t)j * 8 * HID + k0),
                (__attribute__((address_space(3))) void*)(&Bs[wave * 32 + j * 8][0]),
                16, 0, 0);
        }
        // A: fp32 -> bf16 via v_cvt_pk (4 insts per 8 floats)
        #pragma unroll
        for (int j = 0; j < 4; ++j) {
            const int row = rbase + j * 32;
            const float4* asrc = (const float4*)(aptr + (size_t)j * 32 * HID + k0);
            float4 a0 = asrc[0];
            float4 a1 = asrc[1];
            uint4 u;
            u.x = cvt_pk(a0.x, a0.y); u.y = cvt_pk(a0.z, a0.w);
            u.z = cvt_pk(a1.x, a1.y); u.w = cvt_pk(a1.z, a1.w);
            *(uint4*)&As[row][kc] = u;
        }
        __syncthreads();
        #pragma unroll
        for (int kh = 0; kh < 2; ++kh) {
            bf16x8 af[4], bfr[4];
            #pragma unroll
            for (int mi = 0; mi < 4; ++mi)
                af[mi] = *(const bf16x8*)&As[wm * 64 + mi * 16 + l15][kh * 32 + q * 8];
            #pragma unroll
            for (int ni = 0; ni < 4; ++ni) {
                const int r    = wn * 64 + ni * 16 + l15;
                const int slot = (kh * 4 + q) ^ (r & 7);   // un-swizzle
                bfr[ni] = *(const bf16x8*)&Bs[r][slot * 8];
            }
            #pragma unroll
            for (int mi = 0; mi < 4; ++mi)
                #pragma unroll
                for (int ni = 0; ni < 4; ++ni)
                    acc[mi][ni] = __builtin_amdgcn_mfma_f32_16x16x32_bf16(
                        af[mi], bfr[ni], acc[mi][ni], 0, 0, 0);
        }
        __syncthreads();
    }

    // epilogue: per-lane ctx-weighted tanh partial over this wave's 64 cols
    float ps[16];
    #pragma unroll
    for (int mi = 0; mi < 4; ++mi)
        #pragma unroll
        for (int r = 0; r < 4; ++r) {
            float s = 0.f;
            #pragma unroll
            for (int ni = 0; ni < 4; ++ni) {
                const int o = nt * BN + wn * 64 + ni * 16 + l15;
                float y = acc[mi][ni][r] + bias[o];
                s += ctx[o] * tanh_fast(y);
            }
            ps[mi * 4 + r] = s;
        }
    // reduce across the 16 cols held by lanes sharing q (xor masks < 16)
    #pragma unroll
    for (int off = 1; off < 16; off <<= 1)
        #pragma unroll
        for (int i = 0; i < 16; ++i)
            ps[i] += __shfl_xor(ps[i], off, 64);
    if (l15 == 0) {
        #pragma unroll
        for (int mi = 0; mi < 4; ++mi)
            #pragma unroll
            for (int r = 0; r < 4; ++r) {
                const int m = mt * BM + wm * 64 + mi * 16 + q * 4 + r;
                // sims stored transposed: [b][s] so softmax/attend are coalesced
                atomicAdd(&sims[(size_t)(m & (BATCH - 1)) * SEQ + (m >> 5)],
                          ps[mi * 4 + r]);
            }
    }
}

// ---- kernel 3: softmax over seq, per batch (coalesced [b][s] layout) ----
__global__ __launch_bounds__(256) void softmax_kernel(const float* __restrict__ sims,
                                                      float* __restrict__ probs) {
    const int b = blockIdx.x;
    const int tid = threadIdx.x;
    const int lane = tid & 63, wave = tid >> 6;
    __shared__ float red[4];

    float v[16];
    #pragma unroll
    for (int i = 0; i < 16; ++i) v[i] = sims[(size_t)b * SEQ + i * 256 + tid];

    float mx = -INFINITY;
    #pragma unroll
    for (int i = 0; i < 16; ++i) mx = fmaxf(mx, v[i]);
    #pragma unroll
    for (int off = 32; off >= 1; off >>= 1) mx = fmaxf(mx, __shfl_xor(mx, off, 64));
    if (lane == 0) red[wave] = mx;
    __syncthreads();
    mx = fmaxf(fmaxf(red[0], red[1]), fmaxf(red[2], red[3]));
    __syncthreads();

    float sum = 0.f;
    #pragma unroll
    for (int i = 0; i < 16; ++i) { v[i] = __expf(v[i] - mx); sum += v[i]; }
    #pragma unroll
    for (int off = 32; off >= 1; off >>= 1) sum += __shfl_xor(sum, off, 64);
    if (lane == 0) red[wave] = sum;
    __syncthreads();
    const float inv = 1.0f / (red[0] + red[1] + red[2] + red[3]);

    #pragma unroll
    for (int i = 0; i < 16; ++i)
        probs[(size_t)b * SEQ + i * 256 + tid] = v[i] * inv;
}

// ---- kernel 4: weighted-sum pooling ------------------------------------
__global__ __launch_bounds__(512) void attend_kernel(const float* __restrict__ x,
                                                     const float* __restrict__ probs,
                                                     float* __restrict__ out) {
    const int st = blockIdx.x;   // 0..31 (seq tile of 128)
    const int b  = blockIdx.y;   // 0..31
    const int h  = threadIdx.x;  // 0..511
    __shared__ float p[128];
    if (h < 128) p[h] = probs[(size_t)b * SEQ + st * 128 + h];
    __syncthreads();
    float acc = 0.f;
    const float* xp = x + ((size_t)(st * 128) * BATCH + b) * HID + h;
    #pragma unroll 4
    for (int s = 0; s < 128; ++s)
        acc += p[s] * xp[(size_t)s * BATCH * HID];
    atomicAdd(&out[b * HID + h], acc);
}

extern "C" void kernel_launch(void* const* d_in, const int* in_sizes, int n_in,
                              void* d_out, int out_size, void* d_ws, size_t ws_size,
                              hipStream_t stream) {
    const float* x    = (const float*)d_in[0];
    const float* W    = (const float*)d_in[1];
    const float* bias = (const float*)d_in[2];
    const float* ctx  = (const float*)d_in[3];
    float* out = (float*)d_out;

    unsigned short* Wb = (unsigned short*)d_ws;                        // 512 KB
    float* sims  = (float*)((char*)d_ws + (512 << 10));                // 512 KB
    float* probs = (float*)((char*)d_ws + (1024 << 10));               // 512 KB

    hipMemsetAsync(sims, 0, MTOT * sizeof(float), stream);
    hipMemsetAsync(d_out, 0, (size_t)out_size * sizeof(float), stream);

    cvt_w_kernel<<<256, 256, 0, stream>>>(W, Wb);
    gemm_sim_kernel<<<4096, 256, 0, stream>>>(x, Wb, bias, ctx, sims);
    softmax_kernel<<<32, 256, 0, stream>>>(sims, probs);
    attend_kernel<<<dim3(32, 32), 512, 0, stream>>>(x, probs, out);
}